// Round 10
// baseline (2077.808 us; speedup 1.0000x reference)
//
#include <hip/hip_runtime.h>
#include <hip/hip_bf16.h>

#define BB   32
#define IMG  512
#define PP   16
#define DD   256
#define GG   32
#define NN   1024
#define DQ_  32
#define DF_  1024
#define DEPTH_ 8

using short8  = __attribute__((ext_vector_type(8))) short;
using floatx4 = __attribute__((ext_vector_type(4))) float;

__device__ __forceinline__ float bu2f(unsigned short u) {
    return __uint_as_float(((unsigned int)u) << 16);
}
__device__ __forceinline__ unsigned short f2b(float f) {   // round-to-nearest-even
    unsigned int u = __float_as_uint(f);
    u += 0x7fffu + ((u >> 16) & 1u);
    return (unsigned short)(u >> 16);
}
__device__ __forceinline__ unsigned int pack2(float a, float b) {
    return (unsigned int)f2b(a) | ((unsigned int)f2b(b) << 16);
}
// tanh-form GELU via hardware exp; |err| vs exact erf-form < 1e-3
__device__ __forceinline__ float gelu_fast(float x) {
    float u = 0.7978845608028654f * (x + 0.044715f * x * x * x);
    float t = 1.f - 2.f / (1.f + __expf(2.f * u));
    return 0.5f * x * (1.0f + t);
}
__device__ __forceinline__ float lo16(unsigned int u) {
    return __uint_as_float(u << 16);
}
__device__ __forceinline__ float hi16(unsigned int u) {
    return __uint_as_float(u & 0xffff0000u);
}
__device__ __forceinline__ float dot8(uint4 a, uint4 b) {
    const unsigned int* pa = (const unsigned int*)&a;
    const unsigned int* pb = (const unsigned int*)&b;
    float s = 0.f;
    #pragma unroll
    for (int i = 0; i < 4; ++i)
        s += lo16(pa[i]) * lo16(pb[i]) + hi16(pa[i]) * hi16(pb[i]);
    return s;
}

// ---------------- weight transpose+convert: [L][R][C] f32 -> [L][C][R] bf16 ----------------
__global__ __launch_bounds__(256) void k_wtrans(const float* __restrict__ in,
                                                unsigned short* __restrict__ out,
                                                int R, int C) {
    __shared__ float tile[32][33];
    const int l = blockIdx.z;
    const int r0 = blockIdx.x * 32, c0 = blockIdx.y * 32;
    const int tx = threadIdx.x & 31, ty = threadIdx.x >> 5;
    const float* src = in + (size_t)l * R * C;
    unsigned short* dst = out + (size_t)l * R * C;
    #pragma unroll
    for (int i = 0; i < 4; ++i)
        tile[ty + i * 8][tx] = src[(size_t)(r0 + ty + i * 8) * C + c0 + tx];
    __syncthreads();
    #pragma unroll
    for (int i = 0; i < 4; ++i)
        dst[(size_t)(c0 + ty + i * 8) * R + r0 + tx] = f2b(tile[tx][ty + i * 8]);
}

__global__ __launch_bounds__(256) void k_qktrans(const float* __restrict__ wq,
                                                 const float* __restrict__ wk,
                                                 unsigned short* __restrict__ o) {
    const int l = blockIdx.z, j = blockIdx.x, k = threadIdx.x;
    float v = (j < 32) ? wq[(size_t)l * 8192 + k * 32 + j]
                       : wk[(size_t)l * 8192 + k * 32 + (j - 32)];
    o[((size_t)l * 64 + j) * 256 + k] = f2b(v);
}

__global__ void k_bqk(const float* __restrict__ bq, const float* __restrict__ bk,
                      float* __restrict__ o) {
    const int l = blockIdx.x, j = threadIdx.x;
    o[l * 64 + j] = (j < 32) ? bq[l * 32 + j] : bk[l * 32 + (j - 32)];
}

__global__ __launch_bounds__(256) void k_cvt(const float* __restrict__ in,
                                             unsigned short* __restrict__ out) {
    int i = blockIdx.x * 256 + threadIdx.x;
    out[i] = f2b(in[i]);
}

__global__ __launch_bounds__(256) void k_im2col(const float* __restrict__ x,
                                                unsigned short* __restrict__ xp) {
    const int tok = blockIdx.x;
    const int b  = tok >> 10;
    const int n  = tok & (NN - 1);
    const int gi = n >> 5, gj = n & 31;
    const int pi = threadIdx.x >> 4, pj = threadIdx.x & 15;
    xp[(size_t)tok * 256 + threadIdx.x] =
        f2b(x[(size_t)(b * IMG + gi * PP + pi) * IMG + gj * PP + pj]);
}

// ---------------- 64x64 MFMA GEMM (qk projection only, MODE 2) ----------------
template <int K, int N, int MODE>
__global__ __launch_bounds__(256) void k_gemm(
    const unsigned short* __restrict__ A, const unsigned short* __restrict__ Bt,
    const float* __restrict__ bias, unsigned short* __restrict__ Cb) {
    __shared__ alignas(16) unsigned short As[64 * 32];
    __shared__ alignas(16) unsigned short Bs[64 * 32];
    const int t  = threadIdx.x;
    const int m0 = blockIdx.x * 64, n0 = blockIdx.y * 64;
    const int row = t >> 2, ch = t & 3;
    const unsigned short* ga = A  + (size_t)(m0 + row) * K + ch * 8;
    const unsigned short* gb = Bt + (size_t)(n0 + row) * K + ch * 8;
    const int lane = t & 63, wid = t >> 6;
    const int quad = lane >> 4, r = lane & 15;
    const int wm = (wid >> 1) * 32, wn = (wid & 1) * 32;
    floatx4 acc00 = {0,0,0,0}, acc01 = {0,0,0,0}, acc10 = {0,0,0,0}, acc11 = {0,0,0,0};
    uint4 ra = *(const uint4*)ga;
    uint4 rb = *(const uint4*)gb;
    const int KS = K / 32;
    for (int ks = 0; ks < KS; ++ks) {
        __syncthreads();
        *(uint4*)&As[t * 8] = ra;
        *(uint4*)&Bs[t * 8] = rb;
        __syncthreads();
        if (ks + 1 < KS) {
            ra = *(const uint4*)(ga + (ks + 1) * 32);
            rb = *(const uint4*)(gb + (ks + 1) * 32);
        }
        short8 a0 = *(const short8*)&As[(wm + r) * 32 + quad * 8];
        short8 a1 = *(const short8*)&As[(wm + 16 + r) * 32 + quad * 8];
        short8 b0 = *(const short8*)&Bs[(wn + r) * 32 + quad * 8];
        short8 b1 = *(const short8*)&Bs[(wn + 16 + r) * 32 + quad * 8];
        acc00 = __builtin_amdgcn_mfma_f32_16x16x32_bf16(a0, b0, acc00, 0, 0, 0);
        acc01 = __builtin_amdgcn_mfma_f32_16x16x32_bf16(a0, b1, acc01, 0, 0, 0);
        acc10 = __builtin_amdgcn_mfma_f32_16x16x32_bf16(a1, b0, acc10, 0, 0, 0);
        acc11 = __builtin_amdgcn_mfma_f32_16x16x32_bf16(a1, b1, acc11, 0, 0, 0);
    }
    const int nA = n0 + wn + r;
    const int nB = nA + 16;
    const float bias0 = bias[nA], bias1 = bias[nB];
    #pragma unroll
    for (int i = 0; i < 2; ++i) {
        floatx4 aj0 = i ? acc10 : acc00;
        floatx4 aj1 = i ? acc11 : acc01;
        const int mb = m0 + wm + i * 16 + quad * 4;
        #pragma unroll
        for (int g = 0; g < 4; ++g) {
            const int m = mb + g;
            Cb[(size_t)m * N + nA] = f2b(aj0[g] + bias0);
            Cb[(size_t)m * N + nB] = f2b(aj1[g] + bias1);
        }
    }
}

// ---------------- 128x128 MFMA GEMM, register-staged double buffer (m93-style) ----------
// Prefetch next K-slice into VGPRs while MFMAing current: the global-load
// latency is hidden inside each wave (R8/R9 showed global_load_lds drains
// dominate at this occupancy). MODE 0: Cb=bf16(gelu(acc+bias))
// 1: Cf+=acc+bias  2: Cb=bf16(acc+bias)  3: Cf+=tanh(acc+bias)
// 4: Cf=acc+bias+pos[(m&1023)*N+n]
template <int K, int N, int MODE>
__global__ __launch_bounds__(256) void k_gemm128r(
    const unsigned short* __restrict__ A, const unsigned short* __restrict__ Bt,
    const float* __restrict__ bias, unsigned short* __restrict__ Cb,
    float* __restrict__ Cf, const float* __restrict__ pos) {
    __shared__ alignas(16) unsigned short As[128 * 32];
    __shared__ alignas(16) unsigned short Bs[128 * 32];
    const int t  = threadIdx.x;
    const int m0 = blockIdx.x * 128, n0 = blockIdx.y * 128;
    const int srow = t >> 1, sh = (t & 1) * 16;     // thread stages 32B of one row
    const unsigned short* ga = A  + (size_t)(m0 + srow) * K + sh;
    const unsigned short* gb = Bt + (size_t)(n0 + srow) * K + sh;

    const int lane = t & 63, wid = t >> 6;
    const int quad = lane >> 4, r = lane & 15;
    const int wm = (wid >> 1) * 64, wn = (wid & 1) * 64;

    floatx4 acc[4][4];
    #pragma unroll
    for (int i = 0; i < 4; ++i)
        #pragma unroll
        for (int n = 0; n < 4; ++n) acc[i][n] = floatx4{0.f, 0.f, 0.f, 0.f};

    uint4 ra0 = *(const uint4*)(ga);
    uint4 ra1 = *(const uint4*)(ga + 8);
    uint4 rb0 = *(const uint4*)(gb);
    uint4 rb1 = *(const uint4*)(gb + 8);
    const int KS = K / 32;
    for (int ks = 0; ks < KS; ++ks) {
        __syncthreads();
        *(uint4*)&As[srow * 32 + sh]     = ra0;
        *(uint4*)&As[srow * 32 + sh + 8] = ra1;
        *(uint4*)&Bs[srow * 32 + sh]     = rb0;
        *(uint4*)&Bs[srow * 32 + sh + 8] = rb1;
        __syncthreads();
        if (ks + 1 < KS) {
            ra0 = *(const uint4*)(ga + (ks + 1) * 32);
            ra1 = *(const uint4*)(ga + (ks + 1) * 32 + 8);
            rb0 = *(const uint4*)(gb + (ks + 1) * 32);
            rb1 = *(const uint4*)(gb + (ks + 1) * 32 + 8);
        }
        short8 a[4], b[4];
        #pragma unroll
        for (int i = 0; i < 4; ++i)
            a[i] = *(const short8*)&As[(wm + i * 16 + r) * 32 + quad * 8];
        #pragma unroll
        for (int n = 0; n < 4; ++n)
            b[n] = *(const short8*)&Bs[(wn + n * 16 + r) * 32 + quad * 8];
        #pragma unroll
        for (int i = 0; i < 4; ++i)
            #pragma unroll
            for (int n = 0; n < 4; ++n)
                acc[i][n] = __builtin_amdgcn_mfma_f32_16x16x32_bf16(
                    a[i], b[n], acc[i][n], 0, 0, 0);
    }
    #pragma unroll
    for (int n = 0; n < 4; ++n) {
        const int col = n0 + wn + n * 16 + r;
        const float bs = bias[col];
        #pragma unroll
        for (int i = 0; i < 4; ++i) {
            const int mb = m0 + wm + i * 16 + quad * 4;
            #pragma unroll
            for (int g = 0; g < 4; ++g) {
                const int m = mb + g;
                float v0 = acc[i][n][g] + bs;
                if (MODE == 0)      Cb[(size_t)m * N + col] = f2b(gelu_fast(v0));
                else if (MODE == 1) Cf[(size_t)m * N + col] += v0;
                else if (MODE == 2) Cb[(size_t)m * N + col] = f2b(v0);
                else if (MODE == 3) Cf[(size_t)m * N + col] += tanhf(v0);
                else Cf[(size_t)m * N + col] =
                         v0 + pos[(size_t)(m & (NN - 1)) * N + col];
            }
        }
    }
}

// ---------------- depthwise Laplacian (SAME, zero pad) -> bf16 ----------------
__global__ __launch_bounds__(256) void k_lap(const float* __restrict__ h,
                                             unsigned short* __restrict__ e) {
    int idx = blockIdx.x * 256 + threadIdx.x;
    int n  = (idx >> 8) & (NN - 1);
    int gi = n >> 5, gj = n & 31;
    float c  = h[idx];
    float up = (gi > 0)  ? h[idx - GG * DD] : 0.f;
    float dn = (gi < 31) ? h[idx + GG * DD] : 0.f;
    float lf = (gj > 0)  ? h[idx - DD] : 0.f;
    float rt = (gj < 31) ? h[idx + DD] : 0.f;
    e[idx] = f2b(4.f * c - up - dn - lf - rt);
}

// ---------------- LayerNorm (wave per row) -> bf16 ----------------
__global__ __launch_bounds__(256) void k_ln(
    const float* __restrict__ h, const float* __restrict__ g,
    const float* __restrict__ b, unsigned short* __restrict__ xnb, int layer) {
    const int wid = threadIdx.x >> 6, lane = threadIdx.x & 63;
    const int row = blockIdx.x * 4 + wid;
    const float4 xv = *(const float4*)(h + (size_t)row * DD + lane * 4);
    float s = xv.x + xv.y + xv.z + xv.w;
    #pragma unroll
    for (int o = 32; o; o >>= 1) s += __shfl_xor(s, o, 64);
    const float m = s * (1.f / 256.f);
    float t0 = xv.x - m, t1 = xv.y - m, t2 = xv.z - m, t3 = xv.w - m;
    float s2 = t0 * t0 + t1 * t1 + t2 * t2 + t3 * t3;
    #pragma unroll
    for (int o = 32; o; o >>= 1) s2 += __shfl_xor(s2, o, 64);
    const float r = rsqrtf(s2 * (1.f / 256.f) + 1e-5f);
    const int d0 = lane * 4;
    const float4 gv = *(const float4*)(g + layer * DD + d0);
    const float4 bv = *(const float4*)(b + layer * DD + d0);
    uint2 outp;
    outp.x = pack2(t0 * r * gv.x + bv.x, t1 * r * gv.y + bv.y);
    outp.y = pack2(t2 * r * gv.z + bv.z, t3 * r * gv.w + bv.w);
    *(uint2*)(xnb + (size_t)row * DD + d0) = outp;
}

// ---------------- attention scores + softmax -> P[tok][64] bf16 ----------------
__global__ __launch_bounds__(256) void k_score(
    const unsigned short* __restrict__ qkb, unsigned short* __restrict__ P) {
    const int wid = threadIdx.x >> 6, lane = threadIdx.x & 63;
    const int tok = blockIdx.x * 4 + wid;
    const int b = tok >> 10, n = tok & (NN - 1);
    const int gi = n >> 5, gj = n & 31;
    const uint4* qp = (const uint4*)(qkb + (size_t)tok * 64);
    uint4 q0 = qp[0], q1 = qp[1], q2 = qp[2], q3 = qp[3];
    const int key = (lane < 32) ? (b * NN + gi * 32 + lane)
                                : (b * NN + (lane - 32) * 32 + gj);
    const uint4* kp = (const uint4*)(qkb + (size_t)key * 64 + 32);
    uint4 k0 = kp[0], k1 = kp[1], k2 = kp[2], k3 = kp[3];
    float s = dot8(q0, k0) + dot8(q1, k1) + dot8(q2, k2) + dot8(q3, k3);
    s *= 0.17677669529663687f;                // 1/sqrt(32)
    if (lane >= 32 && (lane - 32) == gi) s -= 1e9f;
    float m = s;
    #pragma unroll
    for (int o = 32; o; o >>= 1) m = fmaxf(m, __shfl_xor(m, o, 64));
    float e = expf(s - m);
    float sum = e;
    #pragma unroll
    for (int o = 32; o; o >>= 1) sum += __shfl_xor(sum, o, 64);
    P[(size_t)tok * 64 + lane] = f2b(e / sum);
}

// ---------------- col A*V: h += gamma*out_col (wave = 2 tokens, prefetched) ----------------
__global__ __launch_bounds__(256) void k_avcol(
    const unsigned short* __restrict__ P, const unsigned short* __restrict__ v,
    float* __restrict__ h, const float* __restrict__ gamma, int layer) {
    const int idx = blockIdx.x;            // b*128 + gj*4 + oct
    const int b = idx >> 7, gj = (idx >> 2) & 31, oct = idx & 3;
    const int wid = threadIdx.x >> 6, lane = threadIdx.x & 63;
    const int d0 = lane * 4;
    uint2 vr[32];
    const unsigned short* vbase = v + ((size_t)(b * NN + gj)) * 256 + d0;
    #pragma unroll
    for (int u = 0; u < 32; ++u)
        vr[u] = *(const uint2*)(vbase + (size_t)u * 32 * 256);
    const float g = gamma[layer];
    size_t hidx[2];
    float4 hv[2];
    unsigned int pa[2][16];
    #pragma unroll
    for (int jj = 0; jj < 2; ++jj) {
        const int gi = oct * 8 + wid * 2 + jj;
        const int tok = b * NN + gi * 32 + gj;
        hidx[jj] = (size_t)tok * 256 + d0;
        const uint4* pp = (const uint4*)(P + (size_t)tok * 64 + 32);
        *(uint4*)(pa[jj])      = pp[0];
        *(uint4*)(pa[jj] + 4)  = pp[1];
        *(uint4*)(pa[jj] + 8)  = pp[2];
        *(uint4*)(pa[jj] + 12) = pp[3];
        hv[jj] = *(const float4*)(h + hidx[jj]);
    }
    #pragma unroll
    for (int jj = 0; jj < 2; ++jj) {
        float o0 = 0.f, o1 = 0.f, o2 = 0.f, o3 = 0.f;
        #pragma unroll
        for (int u = 0; u < 32; ++u) {
            float p = (u & 1) ? hi16(pa[jj][u >> 1]) : lo16(pa[jj][u >> 1]);
            o0 += p * lo16(vr[u].x); o1 += p * hi16(vr[u].x);
            o2 += p * lo16(vr[u].y); o3 += p * hi16(vr[u].y);
        }
        float4 r = hv[jj];
        r.x += g * o0; r.y += g * o1; r.z += g * o2; r.w += g * o3;
        *(float4*)(h + hidx[jj]) = r;
    }
}

// ---------------- row A*V + residual + fused LN2 ----------------
__global__ __launch_bounds__(256) void k_avrow_ln(
    const unsigned short* __restrict__ P, const unsigned short* __restrict__ v,
    float* __restrict__ h, unsigned short* __restrict__ xnb,
    const float* __restrict__ gamma, const float* __restrict__ lg,
    const float* __restrict__ lb, int layer) {
    const int idx = blockIdx.x;            // b*128 + gi*4 + oct
    const int b = idx >> 7, gi = (idx >> 2) & 31, oct = idx & 3;
    const int wid = threadIdx.x >> 6, lane = threadIdx.x & 63;
    const int d0 = lane * 4;
    uint2 vr[32];
    const unsigned short* vbase = v + ((size_t)(b * NN + gi * 32)) * 256 + d0;
    #pragma unroll
    for (int w = 0; w < 32; ++w)
        vr[w] = *(const uint2*)(vbase + (size_t)w * 256);
    const float g = gamma[layer];
    const float4 gv = *(const float4*)(lg + layer * DD + d0);
    const float4 bv = *(const float4*)(lb + layer * DD + d0);
    size_t hidx[2];
    float4 hv[2];
    uint2 xu[2];
    unsigned int pa[2][16];
    #pragma unroll
    for (int jj = 0; jj < 2; ++jj) {
        const int gj = oct * 8 + wid * 2 + jj;
        const int tok = b * NN + gi * 32 + gj;
        hidx[jj] = (size_t)tok * 256 + d0;
        const uint4* pp = (const uint4*)(P + (size_t)tok * 64);
        *(uint4*)(pa[jj])      = pp[0];
        *(uint4*)(pa[jj] + 4)  = pp[1];
        *(uint4*)(pa[jj] + 8)  = pp[2];
        *(uint4*)(pa[jj] + 12) = pp[3];
        hv[jj] = *(const float4*)(h + hidx[jj]);
        xu[jj] = *(const uint2*)(xnb + hidx[jj]);
    }
    #pragma unroll
    for (int jj = 0; jj < 2; ++jj) {
        float o0 = 0.f, o1 = 0.f, o2 = 0.f, o3 = 0.f;
        #pragma unroll
        for (int w = 0; w < 32; ++w) {
            float p = (w & 1) ? hi16(pa[jj][w >> 1]) : lo16(pa[jj][w >> 1]);
            o0 += p * lo16(vr[w].x); o1 += p * hi16(vr[w].x);
            o2 += p * lo16(vr[w].y); o3 += p * hi16(vr[w].y);
        }
        float f0 = hv[jj].x + lo16(xu[jj].x) + g * o0;
        float f1 = hv[jj].y + hi16(xu[jj].x) + g * o1;
        float f2 = hv[jj].z + lo16(xu[jj].y) + g * o2;
        float f3 = hv[jj].w + hi16(xu[jj].y) + g * o3;
        float s = f0 + f1 + f2 + f3;
        #pragma unroll
        for (int o = 32; o; o >>= 1) s += __shfl_xor(s, o, 64);
        const float m = s * (1.f / 256.f);
        float t0 = f0 - m, t1 = f1 - m, t2 = f2 - m, t3 = f3 - m;
        float s2 = t0 * t0 + t1 * t1 + t2 * t2 + t3 * t3;
        #pragma unroll
        for (int o = 32; o; o >>= 1) s2 += __shfl_xor(s2, o, 64);
        const float r = rsqrtf(s2 * (1.f / 256.f) + 1e-5f);
        float4 hvout = {f0, f1, f2, f3};
        *(float4*)(h + hidx[jj]) = hvout;
        uint2 outp;
        outp.x = pack2(t0 * r * gv.x + bv.x, t1 * r * gv.y + bv.y);
        outp.y = pack2(t2 * r * gv.z + bv.z, t3 * r * gv.w + bv.w);
        *(uint2*)(xnb + hidx[jj]) = outp;
    }
}

// ---------------- head ----------------
__global__ __launch_bounds__(256) void k_head(
    const float* __restrict__ h, const float* __restrict__ wh,
    const float* __restrict__ bh, float* __restrict__ out) {
    const int tok  = blockIdx.x * 4 + (threadIdx.x >> 6);
    const int lane = threadIdx.x & 63;
    float acc = 0.f;
    #pragma unroll
    for (int i = 0; i < 4; ++i)
        acc += h[(size_t)tok * DD + lane + 64 * i] * wh[lane + 64 * i];
    #pragma unroll
    for (int o = 32; o; o >>= 1) acc += __shfl_down(acc, o, 64);
    if (lane == 0) out[tok] = acc + bh[0];
}

extern "C" void kernel_launch(void* const* d_in, const int* in_sizes, int n_in,
                              void* d_out, int out_size, void* d_ws, size_t ws_size,
                              hipStream_t stream) {
    const float* fx   = (const float*)d_in[0];
    const float* fwp  = (const float*)d_in[1];
    const float* fbp  = (const float*)d_in[2];
    const float* fpos = (const float*)d_in[3];
    const float* fwe  = (const float*)d_in[4];
    const float* fbe  = (const float*)d_in[5];
    const float* flg  = (const float*)d_in[6];
    const float* flb  = (const float*)d_in[7];
    const float* fwq  = (const float*)d_in[8];
    const float* fbq  = (const float*)d_in[9];
    const float* fwk  = (const float*)d_in[10];
    const float* fbk  = (const float*)d_in[11];
    const float* fwv  = (const float*)d_in[12];
    const float* fbv  = (const float*)d_in[13];
    const float* fgam = (const float*)d_in[14];
    const float* fw1  = (const float*)d_in[15];
    const float* fb1  = (const float*)d_in[16];
    const float* fw2  = (const float*)d_in[17];
    const float* fb2  = (const float*)d_in[18];
    const float* fwh  = (const float*)d_in[19];
    const float* fbh  = (const float*)d_in[20];
    float* out = (float*)d_out;

    // workspace (float offsets); high-water 93.9 MB (R5/R6-proven)
    float* ws = (float*)d_ws;
    float*          h    = ws;                                   // 8,388,608 f
    unsigned short* xnb  = (unsigned short*)(ws + 8388608);      // 32768x256 bf16
    unsigned short* w1t  = (unsigned short*)(ws + 12582912);
    unsigned short* w2t  = (unsigned short*)(ws + 13631488);
    unsigned short* wvT  = (unsigned short*)(ws + 14680064);
    unsigned short* wqkT = (unsigned short*)(ws + 14942208);
    unsigned short* wpb  = (unsigned short*)(ws + 15007744);
    unsigned short* weT  = (unsigned short*)(ws + 15040512);
    float*          bqk  = ws + 15073280;
    float* S = ws + 15073792;
    unsigned short* qkb  = (unsigned short*)S;                   // 32768x64 bf16
    unsigned short* v    = (unsigned short*)(S + 1048576);       // 32768x256 bf16
    unsigned short* P    = (unsigned short*)(S + 5242880);       // 32768x64 bf16
    unsigned short* xp   = (unsigned short*)S;                   // pre-loop
    unsigned short* e    = (unsigned short*)S;                   // pre-loop
    unsigned short* Hc   = (unsigned short*)S;                   // 16384x1024 bf16 (MLP)

    const int TOK = BB * NN;               // 32768

    // one-time weight prep
    k_wtrans<<<dim3(8, 32, 8), 256, 0, stream>>>(fw1, w1t, 256, 1024);
    k_wtrans<<<dim3(32, 8, 8), 256, 0, stream>>>(fw2, w2t, 1024, 256);
    k_wtrans<<<dim3(8, 8, 8),  256, 0, stream>>>(fwv, wvT, 256, 256);
    k_wtrans<<<dim3(8, 8, 1),  256, 0, stream>>>(fwe, weT, 256, 256);
    k_qktrans<<<dim3(64, 1, 8), 256, 0, stream>>>(fwq, fwk, wqkT);
    k_bqk<<<8, 64, 0, stream>>>(fbq, fbk, bqk);
    k_cvt<<<256, 256, 0, stream>>>(fwp, wpb);

    // patch embed (GEMM) + pos
    k_im2col<<<TOK, 256, 0, stream>>>(fx, xp);
    k_gemm128r<256, 256, 4><<<dim3(256, 2), 256, 0, stream>>>(
        xp, wpb, fbp, nullptr, h, fpos);
    // edge tokens
    k_lap<<<TOK, 256, 0, stream>>>(h, e);
    k_gemm128r<256, 256, 3><<<dim3(256, 2), 256, 0, stream>>>(
        e, weT, fbe, nullptr, h, nullptr);

    for (int l = 0; l < DEPTH_; ++l) {
        k_ln<<<TOK / 4, 256, 0, stream>>>(h, flg, flb, xnb, l);
        k_gemm<256, 64, 2><<<dim3(512, 1), 256, 0, stream>>>(
            xnb, wqkT + (size_t)l * 16384, bqk + l * 64, qkb);
        k_gemm128r<256, 256, 2><<<dim3(256, 2), 256, 0, stream>>>(
            xnb, wvT + (size_t)l * 65536, fbv + l * 256, v, nullptr, nullptr);
        k_score<<<TOK / 4, 256, 0, stream>>>(qkb, P);
        k_avcol<<<4096, 256, 0, stream>>>(P, v, h, fgam, l);
        k_avrow_ln<<<4096, 256, 0, stream>>>(P, v, h, xnb, fgam, flg, flb, l);
        for (int c = 0; c < 2; ++c) {
            k_gemm128r<256, 1024, 0><<<dim3(128, 8), 256, 0, stream>>>(
                xnb + (size_t)c * 16384 * 256, w1t + (size_t)l * 262144,
                fb1 + (size_t)l * 1024, Hc, nullptr, nullptr);
            k_gemm128r<1024, 256, 1><<<dim3(128, 2), 256, 0, stream>>>(
                Hc, w2t + (size_t)l * 262144,
                fb2 + (size_t)l * 256, nullptr, h + (size_t)c * 16384 * 256, nullptr);
        }
    }

    k_head<<<TOK / 4, 256, 0, stream>>>(h, fwh, fbh, out);
}

// Round 11
// 1792.559 us; speedup vs baseline: 1.1591x; 1.1591x over previous
//
#include <hip/hip_runtime.h>
#include <hip/hip_bf16.h>

#define BB   32
#define IMG  512
#define PP   16
#define DD   256
#define GG   32
#define NN   1024
#define DQ_  32
#define DF_  1024
#define DEPTH_ 8

using short8  = __attribute__((ext_vector_type(8))) short;
using floatx4 = __attribute__((ext_vector_type(4))) float;

__device__ __forceinline__ float bu2f(unsigned short u) {
    return __uint_as_float(((unsigned int)u) << 16);
}
__device__ __forceinline__ unsigned short f2b(float f) {   // round-to-nearest-even
    unsigned int u = __float_as_uint(f);
    u += 0x7fffu + ((u >> 16) & 1u);
    return (unsigned short)(u >> 16);
}
__device__ __forceinline__ unsigned int pack2(float a, float b) {
    return (unsigned int)f2b(a) | ((unsigned int)f2b(b) << 16);
}
// tanh-form GELU via hardware exp; |err| vs exact erf-form < 1e-3 (thr 0.221)
__device__ __forceinline__ float gelu_fast(float x) {
    float u = 0.7978845608028654f * (x + 0.044715f * x * x * x);
    float t = 1.f - 2.f / (1.f + __expf(2.f * u));
    return 0.5f * x * (1.0f + t);
}
__device__ __forceinline__ float lo16(unsigned int u) {
    return __uint_as_float(u << 16);
}
__device__ __forceinline__ float hi16(unsigned int u) {
    return __uint_as_float(u & 0xffff0000u);
}
__device__ __forceinline__ float dot8(uint4 a, uint4 b) {
    const unsigned int* pa = (const unsigned int*)&a;
    const unsigned int* pb = (const unsigned int*)&b;
    float s = 0.f;
    #pragma unroll
    for (int i = 0; i < 4; ++i)
        s += lo16(pa[i]) * lo16(pb[i]) + hi16(pa[i]) * hi16(pb[i]);
    return s;
}

// ---------------- weight transpose+convert: [L][R][C] f32 -> [L][C][R] bf16 ----------------
__global__ __launch_bounds__(256) void k_wtrans(const float* __restrict__ in,
                                                unsigned short* __restrict__ out,
                                                int R, int C) {
    __shared__ float tile[32][33];
    const int l = blockIdx.z;
    const int r0 = blockIdx.x * 32, c0 = blockIdx.y * 32;
    const int tx = threadIdx.x & 31, ty = threadIdx.x >> 5;
    const float* src = in + (size_t)l * R * C;
    unsigned short* dst = out + (size_t)l * R * C;
    #pragma unroll
    for (int i = 0; i < 4; ++i)
        tile[ty + i * 8][tx] = src[(size_t)(r0 + ty + i * 8) * C + c0 + tx];
    __syncthreads();
    #pragma unroll
    for (int i = 0; i < 4; ++i)
        dst[(size_t)(c0 + ty + i * 8) * R + r0 + tx] = f2b(tile[tx][ty + i * 8]);
}

__global__ __launch_bounds__(256) void k_qktrans(const float* __restrict__ wq,
                                                 const float* __restrict__ wk,
                                                 unsigned short* __restrict__ o) {
    const int l = blockIdx.z, j = blockIdx.x, k = threadIdx.x;
    float v = (j < 32) ? wq[(size_t)l * 8192 + k * 32 + j]
                       : wk[(size_t)l * 8192 + k * 32 + (j - 32)];
    o[((size_t)l * 64 + j) * 256 + k] = f2b(v);
}

__global__ void k_bqk(const float* __restrict__ bq, const float* __restrict__ bk,
                      float* __restrict__ o) {
    const int l = blockIdx.x, j = threadIdx.x;
    o[l * 64 + j] = (j < 32) ? bq[l * 32 + j] : bk[l * 32 + (j - 32)];
}

__global__ __launch_bounds__(256) void k_cvt(const float* __restrict__ in,
                                             unsigned short* __restrict__ out) {
    int i = blockIdx.x * 256 + threadIdx.x;
    out[i] = f2b(in[i]);
}

__global__ __launch_bounds__(256) void k_im2col(const float* __restrict__ x,
                                                unsigned short* __restrict__ xp) {
    const int tok = blockIdx.x;
    const int b  = tok >> 10;
    const int n  = tok & (NN - 1);
    const int gi = n >> 5, gj = n & 31;
    const int pi = threadIdx.x >> 4, pj = threadIdx.x & 15;
    xp[(size_t)tok * 256 + threadIdx.x] =
        f2b(x[(size_t)(b * IMG + gi * PP + pi) * IMG + gj * PP + pj]);
}

// ---------------- 64x64 MFMA GEMM (R6-proven config): C[M,N] = A[M,K] @ Bt[N,K]^T ----
// MODE 0: Cb=bf16(gelu(acc+bias))  1: Cf+=acc+bias  2: Cb=bf16(acc+bias)
// MODE 3: Cf+=tanh(acc+bias)       4: Cf=acc+bias+pos[(m&1023)*N+n]
template <int K, int N, int MODE>
__global__ __launch_bounds__(256) void k_gemm(
    const unsigned short* __restrict__ A, const unsigned short* __restrict__ Bt,
    const float* __restrict__ bias, unsigned short* __restrict__ Cb,
    float* __restrict__ Cf, const float* __restrict__ pos) {
    __shared__ alignas(16) unsigned short As[64 * 32];
    __shared__ alignas(16) unsigned short Bs[64 * 32];
    const int t  = threadIdx.x;
    const int m0 = blockIdx.x * 64, n0 = blockIdx.y * 64;
    const int row = t >> 2, ch = t & 3;
    const unsigned short* ga = A  + (size_t)(m0 + row) * K + ch * 8;
    const unsigned short* gb = Bt + (size_t)(n0 + row) * K + ch * 8;

    const int lane = t & 63, wid = t >> 6;
    const int quad = lane >> 4, r = lane & 15;
    const int wm = (wid >> 1) * 32, wn = (wid & 1) * 32;

    floatx4 acc00 = {0.f, 0.f, 0.f, 0.f}, acc01 = {0.f, 0.f, 0.f, 0.f};
    floatx4 acc10 = {0.f, 0.f, 0.f, 0.f}, acc11 = {0.f, 0.f, 0.f, 0.f};

    uint4 ra = *(const uint4*)ga;
    uint4 rb = *(const uint4*)gb;
    const int KS = K / 32;
    for (int ks = 0; ks < KS; ++ks) {
        __syncthreads();
        *(uint4*)&As[t * 8] = ra;
        *(uint4*)&Bs[t * 8] = rb;
        __syncthreads();
        if (ks + 1 < KS) {
            ra = *(const uint4*)(ga + (ks + 1) * 32);
            rb = *(const uint4*)(gb + (ks + 1) * 32);
        }
        short8 a0 = *(const short8*)&As[(wm + r) * 32 + quad * 8];
        short8 a1 = *(const short8*)&As[(wm + 16 + r) * 32 + quad * 8];
        short8 b0 = *(const short8*)&Bs[(wn + r) * 32 + quad * 8];
        short8 b1 = *(const short8*)&Bs[(wn + 16 + r) * 32 + quad * 8];
        acc00 = __builtin_amdgcn_mfma_f32_16x16x32_bf16(a0, b0, acc00, 0, 0, 0);
        acc01 = __builtin_amdgcn_mfma_f32_16x16x32_bf16(a0, b1, acc01, 0, 0, 0);
        acc10 = __builtin_amdgcn_mfma_f32_16x16x32_bf16(a1, b0, acc10, 0, 0, 0);
        acc11 = __builtin_amdgcn_mfma_f32_16x16x32_bf16(a1, b1, acc11, 0, 0, 0);
    }
    const int nA = n0 + wn + r;
    const int nB = nA + 16;
    const float bias0 = bias[nA], bias1 = bias[nB];
    #pragma unroll
    for (int i = 0; i < 2; ++i) {
        floatx4 aj0 = i ? acc10 : acc00;
        floatx4 aj1 = i ? acc11 : acc01;
        const int mb = m0 + wm + i * 16 + quad * 4;
        #pragma unroll
        for (int g = 0; g < 4; ++g) {
            const int m = mb + g;
            float v0 = aj0[g] + bias0, v1 = aj1[g] + bias1;
            if (MODE == 0) {
                Cb[(size_t)m * N + nA] = f2b(gelu_fast(v0));
                Cb[(size_t)m * N + nB] = f2b(gelu_fast(v1));
            } else if (MODE == 1) {
                Cf[(size_t)m * N + nA] += v0;
                Cf[(size_t)m * N + nB] += v1;
            } else if (MODE == 2) {
                Cb[(size_t)m * N + nA] = f2b(v0);
                Cb[(size_t)m * N + nB] = f2b(v1);
            } else if (MODE == 3) {
                Cf[(size_t)m * N + nA] += tanhf(v0);
                Cf[(size_t)m * N + nB] += tanhf(v1);
            } else {
                Cf[(size_t)m * N + nA] = v0 + pos[(size_t)(m & (NN - 1)) * N + nA];
                Cf[(size_t)m * N + nB] = v1 + pos[(size_t)(m & (NN - 1)) * N + nB];
            }
        }
    }
}

// ---------------- depthwise Laplacian (SAME, zero pad) -> bf16 ----------------
__global__ __launch_bounds__(256) void k_lap(const float* __restrict__ h,
                                             unsigned short* __restrict__ e) {
    int idx = blockIdx.x * 256 + threadIdx.x;
    int n  = (idx >> 8) & (NN - 1);
    int gi = n >> 5, gj = n & 31;
    float c  = h[idx];
    float up = (gi > 0)  ? h[idx - GG * DD] : 0.f;
    float dn = (gi < 31) ? h[idx + GG * DD] : 0.f;
    float lf = (gj > 0)  ? h[idx - DD] : 0.f;
    float rt = (gj < 31) ? h[idx + DD] : 0.f;
    e[idx] = f2b(4.f * c - up - dn - lf - rt);
}

// ---------------- LayerNorm (wave per row) -> bf16 ----------------
__global__ __launch_bounds__(256) void k_ln(
    const float* __restrict__ h, const float* __restrict__ g,
    const float* __restrict__ b, unsigned short* __restrict__ xnb, int layer) {
    const int wid = threadIdx.x >> 6, lane = threadIdx.x & 63;
    const int row = blockIdx.x * 4 + wid;
    const float4 xv = *(const float4*)(h + (size_t)row * DD + lane * 4);
    float s = xv.x + xv.y + xv.z + xv.w;
    #pragma unroll
    for (int o = 32; o; o >>= 1) s += __shfl_xor(s, o, 64);
    const float m = s * (1.f / 256.f);
    float t0 = xv.x - m, t1 = xv.y - m, t2 = xv.z - m, t3 = xv.w - m;
    float s2 = t0 * t0 + t1 * t1 + t2 * t2 + t3 * t3;
    #pragma unroll
    for (int o = 32; o; o >>= 1) s2 += __shfl_xor(s2, o, 64);
    const float r = rsqrtf(s2 * (1.f / 256.f) + 1e-5f);
    const int d0 = lane * 4;
    const float4 gv = *(const float4*)(g + layer * DD + d0);
    const float4 bv = *(const float4*)(b + layer * DD + d0);
    uint2 outp;
    outp.x = pack2(t0 * r * gv.x + bv.x, t1 * r * gv.y + bv.y);
    outp.y = pack2(t2 * r * gv.z + bv.z, t3 * r * gv.w + bv.w);
    *(uint2*)(xnb + (size_t)row * DD + d0) = outp;
}

// ---------------- attention scores + softmax -> P[tok][64] bf16 ----------------
__global__ __launch_bounds__(256) void k_score(
    const unsigned short* __restrict__ qkb, unsigned short* __restrict__ P) {
    const int wid = threadIdx.x >> 6, lane = threadIdx.x & 63;
    const int tok = blockIdx.x * 4 + wid;
    const int b = tok >> 10, n = tok & (NN - 1);
    const int gi = n >> 5, gj = n & 31;
    const uint4* qp = (const uint4*)(qkb + (size_t)tok * 64);
    uint4 q0 = qp[0], q1 = qp[1], q2 = qp[2], q3 = qp[3];
    const int key = (lane < 32) ? (b * NN + gi * 32 + lane)
                                : (b * NN + (lane - 32) * 32 + gj);
    const uint4* kp = (const uint4*)(qkb + (size_t)key * 64 + 32);
    uint4 k0 = kp[0], k1 = kp[1], k2 = kp[2], k3 = kp[3];
    float s = dot8(q0, k0) + dot8(q1, k1) + dot8(q2, k2) + dot8(q3, k3);
    s *= 0.17677669529663687f;                // 1/sqrt(32)
    if (lane >= 32 && (lane - 32) == gi) s -= 1e9f;
    float m = s;
    #pragma unroll
    for (int o = 32; o; o >>= 1) m = fmaxf(m, __shfl_xor(m, o, 64));
    float e = expf(s - m);
    float sum = e;
    #pragma unroll
    for (int o = 32; o; o >>= 1) sum += __shfl_xor(sum, o, 64);
    P[(size_t)tok * 64 + lane] = f2b(e / sum);
}

// ---------------- col A*V: h += gamma*out_col (wave = 2 tokens, prefetched) ----------------
__global__ __launch_bounds__(256) void k_avcol(
    const unsigned short* __restrict__ P, const unsigned short* __restrict__ v,
    float* __restrict__ h, const float* __restrict__ gamma, int layer) {
    const int idx = blockIdx.x;            // b*128 + gj*4 + oct
    const int b = idx >> 7, gj = (idx >> 2) & 31, oct = idx & 3;
    const int wid = threadIdx.x >> 6, lane = threadIdx.x & 63;
    const int d0 = lane * 4;
    uint2 vr[32];
    const unsigned short* vbase = v + ((size_t)(b * NN + gj)) * 256 + d0;
    #pragma unroll
    for (int u = 0; u < 32; ++u)
        vr[u] = *(const uint2*)(vbase + (size_t)u * 32 * 256);
    const float g = gamma[layer];
    size_t hidx[2];
    float4 hv[2];
    unsigned int pa[2][16];
    #pragma unroll
    for (int jj = 0; jj < 2; ++jj) {
        const int gi = oct * 8 + wid * 2 + jj;
        const int tok = b * NN + gi * 32 + gj;
        hidx[jj] = (size_t)tok * 256 + d0;
        const uint4* pp = (const uint4*)(P + (size_t)tok * 64 + 32);
        *(uint4*)(pa[jj])      = pp[0];
        *(uint4*)(pa[jj] + 4)  = pp[1];
        *(uint4*)(pa[jj] + 8)  = pp[2];
        *(uint4*)(pa[jj] + 12) = pp[3];
        hv[jj] = *(const float4*)(h + hidx[jj]);
    }
    #pragma unroll
    for (int jj = 0; jj < 2; ++jj) {
        float o0 = 0.f, o1 = 0.f, o2 = 0.f, o3 = 0.f;
        #pragma unroll
        for (int u = 0; u < 32; ++u) {
            float p = (u & 1) ? hi16(pa[jj][u >> 1]) : lo16(pa[jj][u >> 1]);
            o0 += p * lo16(vr[u].x); o1 += p * hi16(vr[u].x);
            o2 += p * lo16(vr[u].y); o3 += p * hi16(vr[u].y);
        }
        float4 r = hv[jj];
        r.x += g * o0; r.y += g * o1; r.z += g * o2; r.w += g * o3;
        *(float4*)(h + hidx[jj]) = r;
    }
}

// ---------------- row A*V + residual + fused LN2 ----------------
__global__ __launch_bounds__(256) void k_avrow_ln(
    const unsigned short* __restrict__ P, const unsigned short* __restrict__ v,
    float* __restrict__ h, unsigned short* __restrict__ xnb,
    const float* __restrict__ gamma, const float* __restrict__ lg,
    const float* __restrict__ lb, int layer) {
    const int idx = blockIdx.x;            // b*128 + gi*4 + oct
    const int b = idx >> 7, gi = (idx >> 2) & 31, oct = idx & 3;
    const int wid = threadIdx.x >> 6, lane = threadIdx.x & 63;
    const int d0 = lane * 4;
    uint2 vr[32];
    const unsigned short* vbase = v + ((size_t)(b * NN + gi * 32)) * 256 + d0;
    #pragma unroll
    for (int w = 0; w < 32; ++w)
        vr[w] = *(const uint2*)(vbase + (size_t)w * 256);
    const float g = gamma[layer];
    const float4 gv = *(const float4*)(lg + layer * DD + d0);
    const float4 bv = *(const float4*)(lb + layer * DD + d0);
    size_t hidx[2];
    float4 hv[2];
    uint2 xu[2];
    unsigned int pa[2][16];
    #pragma unroll
    for (int jj = 0; jj < 2; ++jj) {
        const int gj = oct * 8 + wid * 2 + jj;
        const int tok = b * NN + gi * 32 + gj;
        hidx[jj] = (size_t)tok * 256 + d0;
        const uint4* pp = (const uint4*)(P + (size_t)tok * 64);
        *(uint4*)(pa[jj])      = pp[0];
        *(uint4*)(pa[jj] + 4)  = pp[1];
        *(uint4*)(pa[jj] + 8)  = pp[2];
        *(uint4*)(pa[jj] + 12) = pp[3];
        hv[jj] = *(const float4*)(h + hidx[jj]);
        xu[jj] = *(const uint2*)(xnb + hidx[jj]);
    }
    #pragma unroll
    for (int jj = 0; jj < 2; ++jj) {
        float o0 = 0.f, o1 = 0.f, o2 = 0.f, o3 = 0.f;
        #pragma unroll
        for (int w = 0; w < 32; ++w) {
            float p = (w & 1) ? hi16(pa[jj][w >> 1]) : lo16(pa[jj][w >> 1]);
            o0 += p * lo16(vr[w].x); o1 += p * hi16(vr[w].x);
            o2 += p * lo16(vr[w].y); o3 += p * hi16(vr[w].y);
        }
        float f0 = hv[jj].x + lo16(xu[jj].x) + g * o0;
        float f1 = hv[jj].y + hi16(xu[jj].x) + g * o1;
        float f2 = hv[jj].z + lo16(xu[jj].y) + g * o2;
        float f3 = hv[jj].w + hi16(xu[jj].y) + g * o3;
        float s = f0 + f1 + f2 + f3;
        #pragma unroll
        for (int o = 32; o; o >>= 1) s += __shfl_xor(s, o, 64);
        const float m = s * (1.f / 256.f);
        float t0 = f0 - m, t1 = f1 - m, t2 = f2 - m, t3 = f3 - m;
        float s2 = t0 * t0 + t1 * t1 + t2 * t2 + t3 * t3;
        #pragma unroll
        for (int o = 32; o; o >>= 1) s2 += __shfl_xor(s2, o, 64);
        const float r = rsqrtf(s2 * (1.f / 256.f) + 1e-5f);
        float4 hvout = {f0, f1, f2, f3};
        *(float4*)(h + hidx[jj]) = hvout;
        uint2 outp;
        outp.x = pack2(t0 * r * gv.x + bv.x, t1 * r * gv.y + bv.y);
        outp.y = pack2(t2 * r * gv.z + bv.z, t3 * r * gv.w + bv.w);
        *(uint2*)(xnb + hidx[jj]) = outp;
    }
}

// ---------------- head ----------------
__global__ __launch_bounds__(256) void k_head(
    const float* __restrict__ h, const float* __restrict__ wh,
    const float* __restrict__ bh, float* __restrict__ out) {
    const int tok  = blockIdx.x * 4 + (threadIdx.x >> 6);
    const int lane = threadIdx.x & 63;
    float acc = 0.f;
    #pragma unroll
    for (int i = 0; i < 4; ++i)
        acc += h[(size_t)tok * DD + lane + 64 * i] * wh[lane + 64 * i];
    #pragma unroll
    for (int o = 32; o; o >>= 1) acc += __shfl_down(acc, o, 64);
    if (lane == 0) out[tok] = acc + bh[0];
}

extern "C" void kernel_launch(void* const* d_in, const int* in_sizes, int n_in,
                              void* d_out, int out_size, void* d_ws, size_t ws_size,
                              hipStream_t stream) {
    const float* fx   = (const float*)d_in[0];
    const float* fwp  = (const float*)d_in[1];
    const float* fbp  = (const float*)d_in[2];
    const float* fpos = (const float*)d_in[3];
    const float* fwe  = (const float*)d_in[4];
    const float* fbe  = (const float*)d_in[5];
    const float* flg  = (const float*)d_in[6];
    const float* flb  = (const float*)d_in[7];
    const float* fwq  = (const float*)d_in[8];
    const float* fbq  = (const float*)d_in[9];
    const float* fwk  = (const float*)d_in[10];
    const float* fbk  = (const float*)d_in[11];
    const float* fwv  = (const float*)d_in[12];
    const float* fbv  = (const float*)d_in[13];
    const float* fgam = (const float*)d_in[14];
    const float* fw1  = (const float*)d_in[15];
    const float* fb1  = (const float*)d_in[16];
    const float* fw2  = (const float*)d_in[17];
    const float* fb2  = (const float*)d_in[18];
    const float* fwh  = (const float*)d_in[19];
    const float* fbh  = (const float*)d_in[20];
    float* out = (float*)d_out;

    // workspace (float offsets); high-water 93.9 MB (R5-R10 proven)
    float* ws = (float*)d_ws;
    float*          h    = ws;                                   // 8,388,608 f
    unsigned short* xnb  = (unsigned short*)(ws + 8388608);      // 32768x256 bf16
    unsigned short* w1t  = (unsigned short*)(ws + 12582912);
    unsigned short* w2t  = (unsigned short*)(ws + 13631488);
    unsigned short* wvT  = (unsigned short*)(ws + 14680064);
    unsigned short* wqkT = (unsigned short*)(ws + 14942208);
    unsigned short* wpb  = (unsigned short*)(ws + 15007744);
    unsigned short* weT  = (unsigned short*)(ws + 15040512);
    float*          bqk  = ws + 15073280;
    float* S = ws + 15073792;
    unsigned short* qkb  = (unsigned short*)S;                   // 32768x64 bf16
    unsigned short* v    = (unsigned short*)(S + 1048576);       // 32768x256 bf16
    unsigned short* P    = (unsigned short*)(S + 5242880);       // 32768x64 bf16
    unsigned short* xp   = (unsigned short*)S;                   // pre-loop
    unsigned short* e    = (unsigned short*)S;                   // pre-loop
    unsigned short* Hc   = (unsigned short*)S;                   // 16384x1024 bf16 (MLP)

    const int TOK = BB * NN;               // 32768

    // one-time weight prep
    k_wtrans<<<dim3(8, 32, 8), 256, 0, stream>>>(fw1, w1t, 256, 1024);
    k_wtrans<<<dim3(32, 8, 8), 256, 0, stream>>>(fw2, w2t, 1024, 256);
    k_wtrans<<<dim3(8, 8, 8),  256, 0, stream>>>(fwv, wvT, 256, 256);
    k_wtrans<<<dim3(8, 8, 1),  256, 0, stream>>>(fwe, weT, 256, 256);
    k_qktrans<<<dim3(64, 1, 8), 256, 0, stream>>>(fwq, fwk, wqkT);
    k_bqk<<<8, 64, 0, stream>>>(fbq, fbk, bqk);
    k_cvt<<<256, 256, 0, stream>>>(fwp, wpb);

    // patch embed (GEMM) + pos
    k_im2col<<<TOK, 256, 0, stream>>>(fx, xp);
    k_gemm<256, 256, 4><<<dim3(512, 4), 256, 0, stream>>>(
        xp, wpb, fbp, nullptr, h, fpos);
    // edge tokens
    k_lap<<<TOK, 256, 0, stream>>>(h, e);
    k_gemm<256, 256, 3><<<dim3(512, 4), 256, 0, stream>>>(
        e, weT, fbe, nullptr, h, nullptr);

    for (int l = 0; l < DEPTH_; ++l) {
        k_ln<<<TOK / 4, 256, 0, stream>>>(h, flg, flb, xnb, l);
        k_gemm<256, 64, 2><<<dim3(512, 1), 256, 0, stream>>>(
            xnb, wqkT + (size_t)l * 16384, bqk + l * 64, qkb, nullptr, nullptr);
        k_gemm<256, 256, 2><<<dim3(512, 4), 256, 0, stream>>>(
            xnb, wvT + (size_t)l * 65536, fbv + l * 256, v, nullptr, nullptr);
        k_score<<<TOK / 4, 256, 0, stream>>>(qkb, P);
        k_avcol<<<4096, 256, 0, stream>>>(P, v, h, fgam, l);
        k_avrow_ln<<<4096, 256, 0, stream>>>(P, v, h, xnb, fgam, flg, flb, l);
        for (int c = 0; c < 2; ++c) {
            k_gemm<256, 1024, 0><<<dim3(256, 16), 256, 0, stream>>>(
                xnb + (size_t)c * 16384 * 256, w1t + (size_t)l * 262144,
                fb1 + (size_t)l * 1024, Hc, nullptr, nullptr);
            k_gemm<1024, 256, 1><<<dim3(256, 4), 256, 0, stream>>>(
                Hc, w2t + (size_t)l * 262144,
                fb2 + (size_t)l * 256, nullptr, h + (size_t)c * 16384 * 256, nullptr);
        }
    }

    k_head<<<TOK / 4, 256, 0, stream>>>(h, fwh, fbh, out);
}